// Round 2
// baseline (152.162 us; speedup 1.0000x reference)
//
#include <hip/hip_runtime.h>

// Per-batch confusion-matrix histogram:
//   gt  = trunc(segmap * 255.0f)   (f32 math, matches numpy/jax)
//   keep: gt != ignore (ignore = n_classes when use_dont_care else -1)
//   hist[b][pred][gt] += 1
//
// B=64, H=W=512, NC=19 -> out_size = 64*361 int32.
// R1 post-mortem: 44us main kernel, VALUBusy 6.8%, HBM 1.5TB/s, bank
// conflicts negligible -> latency-bound. R2: unroll x4 for MLP (8 independent
// 16B loads in flight per thread), partials in d_ws + reduce kernel instead
// of zero-kernel + global atomics.

#define NC2_MAX 361
#define BPB 32  // blocks per batch: 32*64 = 2048 blocks = 8/CU = full residency

__global__ __launch_bounds__(256) void zero_out_kernel(int* __restrict__ out, int n) {
    int i = blockIdx.x * 256 + threadIdx.x;
    if (i < n) out[i] = 0;
}

__device__ __forceinline__ void do_pix(int pe, float se, int nc, int nc2, int ignore,
                                       int* hist) {
    int g = (int)(se * 255.0f);
    if (g != ignore) {
        unsigned bin = (unsigned)(pe * nc + g);
        if (bin < (unsigned)nc2) atomicAdd(&hist[bin], 1);
    }
}

// ---- partials path: each block writes its private 361-bin hist to d_ws ----
__global__ __launch_bounds__(256) void seg_hist_part(
    const int* __restrict__ pred,
    const float* __restrict__ seg,
    const int* __restrict__ ncls_p,
    const int* __restrict__ udc_p,
    int* __restrict__ partials,      // [B][BPB][nc2]
    int npix_per_batch)
{
    __shared__ int hist[NC2_MAX];

    const int nc = ncls_p[0];
    const int nc2 = nc * nc;
    const int ignore = udc_p[0] ? nc : -1;

    const int b = blockIdx.y;
    const int tid = threadIdx.x;

    for (int i = tid; i < NC2_MAX; i += 256) hist[i] = 0;
    __syncthreads();

    const size_t base = (size_t)b * (size_t)npix_per_batch;
    const int4*   p4 = (const int4*)(pred + base);
    const float4* s4 = (const float4*)(seg + base);
    const int nvec = npix_per_batch >> 2;
    const int stride = BPB * 256;

    int i = blockIdx.x * 256 + tid;
    const int nfull = nvec / (4 * stride);  // = 2 for this instance

    for (int t = 0; t < nfull; ++t, i += 4 * stride) {
        // issue all 8 loads before any use -> 128 B/thread in flight
        int4   p0 = p4[i];
        int4   p1 = p4[i + stride];
        int4   p2 = p4[i + 2 * stride];
        int4   p3 = p4[i + 3 * stride];
        float4 s0 = s4[i];
        float4 s1 = s4[i + stride];
        float4 s2 = s4[i + 2 * stride];
        float4 s3 = s4[i + 3 * stride];

        do_pix(p0.x, s0.x, nc, nc2, ignore, hist);
        do_pix(p0.y, s0.y, nc, nc2, ignore, hist);
        do_pix(p0.z, s0.z, nc, nc2, ignore, hist);
        do_pix(p0.w, s0.w, nc, nc2, ignore, hist);
        do_pix(p1.x, s1.x, nc, nc2, ignore, hist);
        do_pix(p1.y, s1.y, nc, nc2, ignore, hist);
        do_pix(p1.z, s1.z, nc, nc2, ignore, hist);
        do_pix(p1.w, s1.w, nc, nc2, ignore, hist);
        do_pix(p2.x, s2.x, nc, nc2, ignore, hist);
        do_pix(p2.y, s2.y, nc, nc2, ignore, hist);
        do_pix(p2.z, s2.z, nc, nc2, ignore, hist);
        do_pix(p2.w, s2.w, nc, nc2, ignore, hist);
        do_pix(p3.x, s3.x, nc, nc2, ignore, hist);
        do_pix(p3.y, s3.y, nc, nc2, ignore, hist);
        do_pix(p3.z, s3.z, nc, nc2, ignore, hist);
        do_pix(p3.w, s3.w, nc, nc2, ignore, hist);
    }
    // generic tail (empty for this instance)
    for (; i < nvec; i += stride) {
        int4 p = p4[i];
        float4 s = s4[i];
        do_pix(p.x, s.x, nc, nc2, ignore, hist);
        do_pix(p.y, s.y, nc, nc2, ignore, hist);
        do_pix(p.z, s.z, nc, nc2, ignore, hist);
        do_pix(p.w, s.w, nc, nc2, ignore, hist);
    }
    __syncthreads();

    int* pout = partials + ((size_t)b * BPB + blockIdx.x) * (size_t)nc2;
    for (int k = tid; k < nc2; k += 256) pout[k] = hist[k];
}

__global__ __launch_bounds__(256) void reduce_part(
    const int* __restrict__ partials, int* __restrict__ out, int nc2)
{
    const int b = blockIdx.x;
    const int* p = partials + (size_t)b * BPB * (size_t)nc2;
    for (int bin = threadIdx.x; bin < nc2; bin += 256) {
        int sum = 0;
        #pragma unroll 8
        for (int j = 0; j < BPB; ++j) sum += p[(size_t)j * nc2 + bin];
        out[(size_t)b * nc2 + bin] = sum;
    }
}

// ---- fallback path (ws too small): R1 atomic kernel ----
__global__ __launch_bounds__(256) void seg_hist_atomic(
    const int* __restrict__ pred, const float* __restrict__ seg,
    const int* __restrict__ ncls_p, const int* __restrict__ udc_p,
    int* __restrict__ out, int npix_per_batch)
{
    __shared__ int hist[NC2_MAX];
    const int nc = ncls_p[0];
    const int nc2 = nc * nc;
    const int ignore = udc_p[0] ? nc : -1;
    const int b = blockIdx.y;
    const int tid = threadIdx.x;
    for (int i = tid; i < NC2_MAX; i += 256) hist[i] = 0;
    __syncthreads();
    const size_t base = (size_t)b * (size_t)npix_per_batch;
    const int4*   p4 = (const int4*)(pred + base);
    const float4* s4 = (const float4*)(seg + base);
    const int nvec = npix_per_batch >> 2;
    for (int i = blockIdx.x * 256 + tid; i < nvec; i += BPB * 256) {
        int4 p = p4[i];
        float4 s = s4[i];
        do_pix(p.x, s.x, nc, nc2, ignore, hist);
        do_pix(p.y, s.y, nc, nc2, ignore, hist);
        do_pix(p.z, s.z, nc, nc2, ignore, hist);
        do_pix(p.w, s.w, nc, nc2, ignore, hist);
    }
    __syncthreads();
    int* gout = out + (size_t)b * (size_t)nc2;
    for (int i = tid; i < nc2; i += 256) {
        int v = hist[i];
        if (v) atomicAdd(&gout[i], v);
    }
}

extern "C" void kernel_launch(void* const* d_in, const int* in_sizes, int n_in,
                              void* d_out, int out_size, void* d_ws, size_t ws_size,
                              hipStream_t stream) {
    const int*   pred = (const int*)d_in[0];
    const float* seg  = (const float*)d_in[1];
    const int*   ncp  = (const int*)d_in[2];
    const int*   udp  = (const int*)d_in[3];
    int* out = (int*)d_out;

    const int total_pix = in_sizes[0];         // B*H*W
    const int B = out_size / 361;              // 64 (nc=19 instance-fixed)
    const int npix_per_batch = total_pix / B;  // 262144
    const int nc2 = out_size / B;              // 361

    const size_t ws_needed = (size_t)B * BPB * nc2 * sizeof(int);

    if (ws_size >= ws_needed) {
        int* partials = (int*)d_ws;
        dim3 grid(BPB, B);
        seg_hist_part<<<grid, 256, 0, stream>>>(pred, seg, ncp, udp, partials,
                                                npix_per_batch);
        reduce_part<<<B, 256, 0, stream>>>(partials, out, nc2);
    } else {
        int nblk = (out_size + 255) / 256;
        zero_out_kernel<<<nblk, 256, 0, stream>>>(out, out_size);
        dim3 grid(BPB, B);
        seg_hist_atomic<<<grid, 256, 0, stream>>>(pred, seg, ncp, udp, out,
                                                  npix_per_batch);
    }
}

// Round 3
// 151.133 us; speedup vs baseline: 1.0068x; 1.0068x over previous
//
#include <hip/hip_runtime.h>

// Per-batch confusion-matrix histogram:
//   gt  = trunc(segmap * 255.0f)   (f32 math, matches numpy/jax)
//   keep: gt != ignore (ignore = n_classes when use_dont_care else -1)
//   hist[b][pred][gt] += 1
//
// R2 post-mortem: VGPR=28 proves compiler defeated the 8-load MLP unroll;
// R1==R2 time. CU is ~88% stalled; SQ_LDS_BANK_CONFLICT = 4.87 cyc/atomic
// (likely per-SE sampled -> ~17us true cost). R3 single-variable test:
// 4-way replicated LDS histogram (copy = tid&3) to cut same-address RMW
// serialization ~4x. Everything else identical to R2.

#define NC2_MAX 361
#define NREP 4
#define BPB 32  // blocks per batch: 32*64 = 2048 blocks = 8/CU

__global__ __launch_bounds__(256) void zero_out_kernel(int* __restrict__ out, int n) {
    int i = blockIdx.x * 256 + threadIdx.x;
    if (i < n) out[i] = 0;
}

__device__ __forceinline__ void do_pix(int pe, float se, int nc, int nc2, int ignore,
                                       int* histc) {
    int g = (int)(se * 255.0f);
    if (g != ignore) {
        unsigned bin = (unsigned)(pe * nc + g);
        if (bin < (unsigned)nc2) atomicAdd(&histc[bin], 1);
    }
}

// ---- partials path: each block writes its private 361-bin hist to d_ws ----
__global__ __launch_bounds__(256) void seg_hist_part(
    const int* __restrict__ pred,
    const float* __restrict__ seg,
    const int* __restrict__ ncls_p,
    const int* __restrict__ udc_p,
    int* __restrict__ partials,      // [B][BPB][nc2]
    int npix_per_batch)
{
    __shared__ int hist[NREP * NC2_MAX];

    const int nc = ncls_p[0];
    const int nc2 = nc * nc;
    const int ignore = udc_p[0] ? nc : -1;

    const int b = blockIdx.y;
    const int tid = threadIdx.x;

    for (int i = tid; i < NREP * NC2_MAX; i += 256) hist[i] = 0;
    __syncthreads();

    // each thread's private sub-histogram copy: cuts same-address LDS RMW
    // collisions ~4x; copies are 361 ints apart -> 9-bank rotation, spread ok
    int* histc = hist + (tid & (NREP - 1)) * NC2_MAX;

    const size_t base = (size_t)b * (size_t)npix_per_batch;
    const int4*   p4 = (const int4*)(pred + base);
    const float4* s4 = (const float4*)(seg + base);
    const int nvec = npix_per_batch >> 2;
    const int stride = BPB * 256;

    int i = blockIdx.x * 256 + tid;
    const int nfull = nvec / (4 * stride);

    for (int t = 0; t < nfull; ++t, i += 4 * stride) {
        int4   p0 = p4[i];
        int4   p1 = p4[i + stride];
        int4   p2 = p4[i + 2 * stride];
        int4   p3 = p4[i + 3 * stride];
        float4 s0 = s4[i];
        float4 s1 = s4[i + stride];
        float4 s2 = s4[i + 2 * stride];
        float4 s3 = s4[i + 3 * stride];

        do_pix(p0.x, s0.x, nc, nc2, ignore, histc);
        do_pix(p0.y, s0.y, nc, nc2, ignore, histc);
        do_pix(p0.z, s0.z, nc, nc2, ignore, histc);
        do_pix(p0.w, s0.w, nc, nc2, ignore, histc);
        do_pix(p1.x, s1.x, nc, nc2, ignore, histc);
        do_pix(p1.y, s1.y, nc, nc2, ignore, histc);
        do_pix(p1.z, s1.z, nc, nc2, ignore, histc);
        do_pix(p1.w, s1.w, nc, nc2, ignore, histc);
        do_pix(p2.x, s2.x, nc, nc2, ignore, histc);
        do_pix(p2.y, s2.y, nc, nc2, ignore, histc);
        do_pix(p2.z, s2.z, nc, nc2, ignore, histc);
        do_pix(p2.w, s2.w, nc, nc2, ignore, histc);
        do_pix(p3.x, s3.x, nc, nc2, ignore, histc);
        do_pix(p3.y, s3.y, nc, nc2, ignore, histc);
        do_pix(p3.z, s3.z, nc, nc2, ignore, histc);
        do_pix(p3.w, s3.w, nc, nc2, ignore, histc);
    }
    for (; i < nvec; i += stride) {
        int4 p = p4[i];
        float4 s = s4[i];
        do_pix(p.x, s.x, nc, nc2, ignore, histc);
        do_pix(p.y, s.y, nc, nc2, ignore, histc);
        do_pix(p.z, s.z, nc, nc2, ignore, histc);
        do_pix(p.w, s.w, nc, nc2, ignore, histc);
    }
    __syncthreads();

    int* pout = partials + ((size_t)b * BPB + blockIdx.x) * (size_t)nc2;
    for (int k = tid; k < nc2; k += 256) {
        int v = hist[k];
        #pragma unroll
        for (int r = 1; r < NREP; ++r) v += hist[r * NC2_MAX + k];
        pout[k] = v;
    }
}

__global__ __launch_bounds__(256) void reduce_part(
    const int* __restrict__ partials, int* __restrict__ out, int nc2)
{
    const int b = blockIdx.x;
    const int* p = partials + (size_t)b * BPB * (size_t)nc2;
    for (int bin = threadIdx.x; bin < nc2; bin += 256) {
        int sum = 0;
        #pragma unroll 8
        for (int j = 0; j < BPB; ++j) sum += p[(size_t)j * nc2 + bin];
        out[(size_t)b * nc2 + bin] = sum;
    }
}

// ---- fallback path (ws too small): atomic flush ----
__global__ __launch_bounds__(256) void seg_hist_atomic(
    const int* __restrict__ pred, const float* __restrict__ seg,
    const int* __restrict__ ncls_p, const int* __restrict__ udc_p,
    int* __restrict__ out, int npix_per_batch)
{
    __shared__ int hist[NREP * NC2_MAX];
    const int nc = ncls_p[0];
    const int nc2 = nc * nc;
    const int ignore = udc_p[0] ? nc : -1;
    const int b = blockIdx.y;
    const int tid = threadIdx.x;
    for (int i = tid; i < NREP * NC2_MAX; i += 256) hist[i] = 0;
    __syncthreads();
    int* histc = hist + (tid & (NREP - 1)) * NC2_MAX;
    const size_t base = (size_t)b * (size_t)npix_per_batch;
    const int4*   p4 = (const int4*)(pred + base);
    const float4* s4 = (const float4*)(seg + base);
    const int nvec = npix_per_batch >> 2;
    for (int i = blockIdx.x * 256 + tid; i < nvec; i += BPB * 256) {
        int4 p = p4[i];
        float4 s = s4[i];
        do_pix(p.x, s.x, nc, nc2, ignore, histc);
        do_pix(p.y, s.y, nc, nc2, ignore, histc);
        do_pix(p.z, s.z, nc, nc2, ignore, histc);
        do_pix(p.w, s.w, nc, nc2, ignore, histc);
    }
    __syncthreads();
    int* gout = out + (size_t)b * (size_t)nc2;
    for (int i = tid; i < nc2; i += 256) {
        int v = hist[i];
        #pragma unroll
        for (int r = 1; r < NREP; ++r) v += hist[r * NC2_MAX + i];
        if (v) atomicAdd(&gout[i], v);
    }
}

extern "C" void kernel_launch(void* const* d_in, const int* in_sizes, int n_in,
                              void* d_out, int out_size, void* d_ws, size_t ws_size,
                              hipStream_t stream) {
    const int*   pred = (const int*)d_in[0];
    const float* seg  = (const float*)d_in[1];
    const int*   ncp  = (const int*)d_in[2];
    const int*   udp  = (const int*)d_in[3];
    int* out = (int*)d_out;

    const int total_pix = in_sizes[0];         // B*H*W
    const int B = out_size / 361;              // 64 (nc=19 instance-fixed)
    const int npix_per_batch = total_pix / B;  // 262144
    const int nc2 = out_size / B;              // 361

    const size_t ws_needed = (size_t)B * BPB * nc2 * sizeof(int);

    if (ws_size >= ws_needed) {
        int* partials = (int*)d_ws;
        dim3 grid(BPB, B);
        seg_hist_part<<<grid, 256, 0, stream>>>(pred, seg, ncp, udp, partials,
                                                npix_per_batch);
        reduce_part<<<B, 256, 0, stream>>>(partials, out, nc2);
    } else {
        int nblk = (out_size + 255) / 256;
        zero_out_kernel<<<nblk, 256, 0, stream>>>(out, out_size);
        dim3 grid(BPB, B);
        seg_hist_atomic<<<grid, 256, 0, stream>>>(pred, seg, ncp, udp, out,
                                                  npix_per_batch);
    }
}